// Round 13
// baseline (360.099 us; speedup 1.0000x reference)
//
#include <hip/hip_runtime.h>
#include <hip/hip_bf16.h>

typedef __attribute__((ext_vector_type(8))) short  short8;
typedef __attribute__((ext_vector_type(8))) unsigned short ushort8;
typedef __attribute__((ext_vector_type(4))) unsigned short usv4;
typedef __attribute__((ext_vector_type(4))) float  f32x4;

#define D_DIM 1152
#define O_DIM 256
#define N_TOT 100352
#define XT_H 58
#define XT_ROW (58 * 128)

__device__ __forceinline__ unsigned short f2bf(float f) {
  __hip_bfloat16 h = __float2bfloat16(f);
  return __builtin_bit_cast(unsigned short, h);
}

// ---------------------------------------------------------------------------
// Kernel 1: Wt[o][dn] via LDS-tiled fp32 block-GEMM (proven R4)
// ---------------------------------------------------------------------------
__global__ __launch_bounds__(256) void wt_kernel(
    const float* __restrict__ S1s, const float* __restrict__ U1s,
    const float* __restrict__ U2s, const float* __restrict__ S2s,
    unsigned short* __restrict__ Wt) {
  __shared__ float A_lds[32][64];
  __shared__ float B_lds[32][64];

  const int bo = blockIdx.x & 3;
  const int bd = blockIdx.x >> 2;
  const int o0  = bo << 6;
  const int dn0 = bd << 6;
  const int rr  = dn0 >> 7;
  const int c0  = dn0 & 127;

  const int tid = threadIdx.x;
  const int ty = tid >> 4, tx = tid & 15;

  float acc[4][4] = {};

  for (int kc = 0; kc < 15; ++kc) {
#pragma unroll
    for (int e = 0; e < 8; ++e) {
      const int li = e * 256 + tid;
      const int kk = li >> 6;
      const int xx = li & 63;
      const int k  = kc * 32 + kk;
      float av, bv;
      if (k < 48) {
        av = U1s[k * O_DIM + o0 + xx];
        const int d_old = (c0 + xx) * 9 + rr;
        bv = S1s[(size_t)((k >> 3) * D_DIM + d_old) * 8 + (k & 7)];
      } else {
        const int kq = k - 48;
        av = S2s[(size_t)kq * O_DIM + o0 + xx];
        const int d_old = (c0 + xx) * 9 + rr;
        bv = U2s[(size_t)kq * D_DIM + d_old];
      }
      A_lds[kk][xx] = av;
      B_lds[kk][xx] = bv;
    }
    __syncthreads();
#pragma unroll
    for (int kk = 0; kk < 32; ++kk) {
      f32x4 a = *(const f32x4*)&A_lds[kk][ty << 2];
      f32x4 b = *(const f32x4*)&B_lds[kk][tx << 2];
#pragma unroll
      for (int i = 0; i < 4; ++i)
#pragma unroll
        for (int j = 0; j < 4; ++j)
          acc[i][j] += a[i] * b[j];
    }
    __syncthreads();
  }

#pragma unroll
  for (int i = 0; i < 4; ++i) {
    usv4 v;
#pragma unroll
    for (int j = 0; j < 4; ++j) v[j] = f2bf(acc[i][j] * (1.0f / 6.0f));
    *(usv4*)(Wt + (size_t)(o0 + (ty << 2) + i) * D_DIM + dn0 + (tx << 2)) = v;
  }
}

// ---------------------------------------------------------------------------
// Kernel 2: pad+transpose x[B,C,H,W] fp32 -> x_t[b][ih][iw][c] bf16 (proven R4)
// ---------------------------------------------------------------------------
__global__ __launch_bounds__(256) void pad_kernel(const float* __restrict__ x,
                                                  unsigned short* __restrict__ xt) {
  int blk = blockIdx.x;
  int b = blk / XT_H, ih = blk - b * XT_H;
  unsigned short* dst = xt + (size_t)blk * XT_ROW;
  int tid = threadIdx.x;

  if (ih == 0 || ih == XT_H - 1) {
    ushort8 z;
#pragma unroll
    for (int q = 0; q < 8; ++q) z[q] = 0;
    for (int i = tid; i < XT_ROW / 8; i += 256) ((ushort8*)dst)[i] = z;
    return;
  }

  __shared__ unsigned short lds[128 * 58];
  int h = ih - 1;
  const float* xb = x + (size_t)b * 128 * 3136 + (size_t)h * 56;
#pragma unroll 4
  for (int r = 0; r < 28; ++r) {
    int idx = r * 256 + tid;
    int c = idx / 56, w2 = idx - c * 56;
    lds[c * 58 + w2] = f2bf(xb[(size_t)c * 3136 + w2]);
  }
  __syncthreads();
#pragma unroll 4
  for (int r = 0; r < 29; ++r) {
    int idx = r * 256 + tid;
    int iw = idx >> 7, c = idx & 127;
    unsigned short v = 0;
    if (iw >= 1 && iw <= 56) v = lds[c * 58 + (iw - 1)];
    dst[idx] = v;
  }
}

// ---------------------------------------------------------------------------
// Kernel 3: implicit-im2col GEMM, REGISTER-DIRECT, barrier-free.
// Rationale: MFMA floor for this shape is ~28.5us (4.85 cyc/MFMA per CU);
// all LDS-staged variants sat at MfmaUtil 20-25% because barrier-locked
// waves stall the matrix pipe together. Here fragments are loaded straight
// from global (A: Wt 590KB L2/L1-resident; B: xt slab L2-resident per XCD),
// no LDS, no barriers: each wave prefetches K-slice s+1's 16 fragment loads
// under slice s's 64 MFMAs (~1240 cyc/SIMD covers ~300-600 cyc latency).
// Wave-tile 128x128 (acc[8][8] -> AGPRs), 4-wave blocks (2x2) so co-located
// waves share A/B cache lines via L1; grid 392 (XCD-swizzled n-ranges).
// ---------------------------------------------------------------------------
__device__ __forceinline__ int koffB(int s) {
  // element offset within an xt row-group for K-slice s (32 channels):
  // rr = s>>2 in 0..8 ; kh = rr/3 ; kw = rr%3
  const int rr = s >> 2;
  const int kh = (rr * 11) >> 5;
  const int kw = rr - kh * 3;
  return (kh * XT_H + kw) * 128 + (((s >> 1) & 1) << 6) + ((s & 1) << 5);
}

#define LOADA(dst, s_) do {                                                    \
  const unsigned short* _pa = pA + (s_) * 32;                                  \
  _Pragma("unroll")                                                            \
  for (int mi = 0; mi < 8; ++mi)                                               \
    dst[mi] = *(const short8*)(_pa + mi * (16 * D_DIM));                       \
} while (0)

#define LOADB(dst, s_) do {                                                    \
  const int _kb = koffB(s_);                                                   \
  _Pragma("unroll")                                                            \
  for (int ni = 0; ni < 8; ++ni)                                               \
    dst[ni] = *(const short8*)(pB[ni] + _kb);                                  \
} while (0)

#define MFMA_ALL(A_, B_) do {                                                  \
  _Pragma("unroll")                                                            \
  for (int mi = 0; mi < 8; ++mi)                                               \
    _Pragma("unroll")                                                          \
    for (int ni = 0; ni < 8; ++ni)                                             \
      acc[mi][ni] = __builtin_amdgcn_mfma_f32_16x16x32_bf16(                   \
          A_[mi], B_[ni], acc[mi][ni], 0, 0, 0);                               \
} while (0)

__global__ __launch_bounds__(256, 1) void gemm_kernel(
    const unsigned short* __restrict__ Wt, const unsigned short* __restrict__ xt,
    const float* __restrict__ bias, float* __restrict__ out) {
  // XCD swizzle (392 % 8 == 0): each XCD gets 49 consecutive n-tiles.
  const int bid   = blockIdx.x;
  const int ntile = (bid & 7) * 49 + (bid >> 3);
  const int n0    = ntile << 8;

  const int tid  = threadIdx.x;
  const int lane = tid & 63;
  const int w    = tid >> 6;
  const int o_w  = (w >> 1) << 7;          // wave o base: 0 | 128
  const int n_w  = n0 + ((w & 1) << 7);    // wave n base
  const int la15 = lane & 15;
  const int kq8  = (lane >> 4) << 3;       // lane k-offset within slice (elems)

  // per-lane fragment base pointers
  const unsigned short* pA = Wt + (size_t)(o_w + la15) * D_DIM + kq8;
  const unsigned short* pB[8];
#pragma unroll
  for (int ni = 0; ni < 8; ++ni) {
    const int n_g = n_w + ni * 16 + la15;
    const int b   = n_g / 3136;
    const int s   = n_g - b * 3136;
    const int oh  = s / 56, ow = s - oh * 56;
    pB[ni] = xt + (((size_t)b * XT_H + oh) * XT_H + ow) * 128 + kq8;
  }

  f32x4 acc[8][8] = {};
  short8 aP[8], bP[8], aQ[8], bQ[8];

  // prologue: slice 0 into ping
  LOADA(aP, 0);
  LOADB(bP, 0);

  for (int s = 0; s < 36; s += 2) {
    // prefetch slice s+1 into pong (s+1 <= 35 always since s <= 34)
    LOADA(aQ, s + 1);
    LOADB(bQ, s + 1);
    MFMA_ALL(aP, bP);
    // prefetch slice s+2 into ping (clamped; last iter reloads 35, unused)
    const int s2 = (s + 2 < 36) ? s + 2 : 35;
    LOADA(aP, s2);
    LOADB(bP, s2);
    MFMA_ALL(aQ, bQ);
  }

  // epilogue: D row = o (o_w + mi*16 + (lane>>4)*4 + r), col = n (la15)
  const int lr = (lane >> 4) << 2;
#pragma unroll
  for (int ni = 0; ni < 8; ++ni) {
    const int ng = n_w + ni * 16 + la15;
    const int b  = ng / 3136;
    const int s  = ng - b * 3136;
    float* op = out + (size_t)b * (O_DIM * 3136) + s;
#pragma unroll
    for (int mi = 0; mi < 8; ++mi) {
      const int og = o_w + mi * 16 + lr;
#pragma unroll
      for (int r = 0; r < 4; ++r)
        op[(size_t)(og + r) * 3136] = acc[mi][ni][r] + 2.0f * bias[og + r];
    }
  }
}

// ---------------------------------------------------------------------------
extern "C" void kernel_launch(void* const* d_in, const int* in_sizes, int n_in,
                              void* d_out, int out_size, void* d_ws, size_t ws_size,
                              hipStream_t stream) {
  const float* x    = (const float*)d_in[0];
  const float* S1s  = (const float*)d_in[1];
  const float* U1s  = (const float*)d_in[2];
  const float* U2s  = (const float*)d_in[3];
  const float* S2s  = (const float*)d_in[4];
  const float* bias = (const float*)d_in[5];
  float* out = (float*)d_out;
  (void)ws_size;

  unsigned short* xt = (unsigned short*)d_ws;
  unsigned short* Wt = (unsigned short*)((char*)d_ws + (size_t)32 * XT_H * XT_ROW * 2);

  pad_kernel<<<dim3(32 * XT_H), dim3(256), 0, stream>>>(x, xt);
  wt_kernel<<<dim3(72), dim3(256), 0, stream>>>(S1s, U1s, U2s, S2s, Wt);
  gemm_kernel<<<dim3(392), dim3(256), 0, stream>>>(Wt, xt, bias, out);
}

// Round 14
// 127.629 us; speedup vs baseline: 2.8214x; 2.8214x over previous
//
#include <hip/hip_runtime.h>
#include <hip/hip_bf16.h>

typedef __attribute__((ext_vector_type(8))) short  short8;
typedef __attribute__((ext_vector_type(8))) unsigned short ushort8;
typedef __attribute__((ext_vector_type(4))) unsigned short usv4;
typedef __attribute__((ext_vector_type(4))) float  f32x4;

#define D_DIM 1152
#define O_DIM 256
#define N_TOT 100352
#define XT_H 58
#define XT_ROW (58 * 128)

__device__ __forceinline__ unsigned short f2bf(float f) {
  __hip_bfloat16 h = __float2bfloat16(f);
  return __builtin_bit_cast(unsigned short, h);
}

#define GLOAD_LDS16(g, l)                                              \
  __builtin_amdgcn_global_load_lds(                                    \
      (const __attribute__((address_space(1))) void*)(g),              \
      (__attribute__((address_space(3))) void*)(l), 16, 0, 0)

// ---------------------------------------------------------------------------
// Kernel 1: Wt[o][dn] via LDS-tiled fp32 block-GEMM (proven R4)
// ---------------------------------------------------------------------------
__global__ __launch_bounds__(256) void wt_kernel(
    const float* __restrict__ S1s, const float* __restrict__ U1s,
    const float* __restrict__ U2s, const float* __restrict__ S2s,
    unsigned short* __restrict__ Wt) {
  __shared__ float A_lds[32][64];
  __shared__ float B_lds[32][64];

  const int bo = blockIdx.x & 3;
  const int bd = blockIdx.x >> 2;
  const int o0  = bo << 6;
  const int dn0 = bd << 6;
  const int rr  = dn0 >> 7;
  const int c0  = dn0 & 127;

  const int tid = threadIdx.x;
  const int ty = tid >> 4, tx = tid & 15;

  float acc[4][4] = {};

  for (int kc = 0; kc < 15; ++kc) {
#pragma unroll
    for (int e = 0; e < 8; ++e) {
      const int li = e * 256 + tid;
      const int kk = li >> 6;
      const int xx = li & 63;
      const int k  = kc * 32 + kk;
      float av, bv;
      if (k < 48) {
        av = U1s[k * O_DIM + o0 + xx];
        const int d_old = (c0 + xx) * 9 + rr;
        bv = S1s[(size_t)((k >> 3) * D_DIM + d_old) * 8 + (k & 7)];
      } else {
        const int kq = k - 48;
        av = S2s[(size_t)kq * O_DIM + o0 + xx];
        const int d_old = (c0 + xx) * 9 + rr;
        bv = U2s[(size_t)kq * D_DIM + d_old];
      }
      A_lds[kk][xx] = av;
      B_lds[kk][xx] = bv;
    }
    __syncthreads();
#pragma unroll
    for (int kk = 0; kk < 32; ++kk) {
      f32x4 a = *(const f32x4*)&A_lds[kk][ty << 2];
      f32x4 b = *(const f32x4*)&B_lds[kk][tx << 2];
#pragma unroll
      for (int i = 0; i < 4; ++i)
#pragma unroll
        for (int j = 0; j < 4; ++j)
          acc[i][j] += a[i] * b[j];
    }
    __syncthreads();
  }

#pragma unroll
  for (int i = 0; i < 4; ++i) {
    usv4 v;
#pragma unroll
    for (int j = 0; j < 4; ++j) v[j] = f2bf(acc[i][j] * (1.0f / 6.0f));
    *(usv4*)(Wt + (size_t)(o0 + (ty << 2) + i) * D_DIM + dn0 + (tx << 2)) = v;
  }
}

// ---------------------------------------------------------------------------
// Kernel 2: pad+transpose x[B,C,H,W] fp32 -> x_t[b][ih][iw][c] bf16 (proven R4)
// ---------------------------------------------------------------------------
__global__ __launch_bounds__(256) void pad_kernel(const float* __restrict__ x,
                                                  unsigned short* __restrict__ xt) {
  int blk = blockIdx.x;
  int b = blk / XT_H, ih = blk - b * XT_H;
  unsigned short* dst = xt + (size_t)blk * XT_ROW;
  int tid = threadIdx.x;

  if (ih == 0 || ih == XT_H - 1) {
    ushort8 z;
#pragma unroll
    for (int q = 0; q < 8; ++q) z[q] = 0;
    for (int i = tid; i < XT_ROW / 8; i += 256) ((ushort8*)dst)[i] = z;
    return;
  }

  __shared__ unsigned short lds[128 * 58];
  int h = ih - 1;
  const float* xb = x + (size_t)b * 128 * 3136 + (size_t)h * 56;
#pragma unroll 4
  for (int r = 0; r < 28; ++r) {
    int idx = r * 256 + tid;
    int c = idx / 56, w2 = idx - c * 56;
    lds[c * 58 + w2] = f2bf(xb[(size_t)c * 3136 + w2]);
  }
  __syncthreads();
#pragma unroll 4
  for (int r = 0; r < 29; ++r) {
    int idx = r * 256 + tid;
    int iw = idx >> 7, c = idx & 127;
    unsigned short v = 0;
    if (iw >= 1 && iw <= 56) v = lds[c * 58 + (iw - 1)];
    dst[idx] = v;
  }
}

// ---------------------------------------------------------------------------
// Kernel 3: implicit-im2col GEMM — R7's one-barrier slice ring, resized so
// TWO independent blocks fit per CU (m114 cross-block overlap = m97's hiding
// mechanism). BM=256(o) x BN=128(n), 256 thr / 4 waves (2Mx2N), wave-tile
// 128x64 (acc[8][4]). Pipeline unit = K-slice of 32. Ring of 3 slots x
// [A 256x32 | B 128x32] bf16 = 24KB -> 72KB LDS total (2 blocks/CU; VGPR
// ~210 -> 8 waves/CU fits). Phase s: 12 ds_read_b128 -> stage slice s+2
// (6 gloads) -> vmcnt(6) (slice s+1 landed, s+2 in flight; drains only at
// tail) -> barrier. Slot-overwrite safety: each wave's ds_reads complete
// before its consuming MFMAs issue, which precede its barrier.
// 64B-row swizzle (element-verified): stored granule = g ^ ((row>>1)&3);
// global source pre-swizzled (linear LDS dest), ds_read applies same XOR.
// 16 lanes/granule-column spread over 8 bank-slots = 2-way aliasing = free.
// ---------------------------------------------------------------------------
__device__ __forceinline__ constexpr int KOFS(int s) {
  // xt element offset for K-slice s (32 ch): rr = s>>2 (kh*3+kw), c0=(s&3)*32
  int rr = s >> 2;
  return ((rr / 3) * 58 + (rr % 3)) * 128 + (s & 3) * 32;
}

// stage slice s_ into slot (s_%3): A 4 gloads (64 rows each), B 2 gloads
#define STAGE_S(s_) do {                                                       \
  const int _sl = ((s_) % 3) * 12288;                                          \
  GLOAD_LDS16(pA[0] + (s_) * 32, smem + _sl + (tid << 3));                     \
  GLOAD_LDS16(pA[1] + (s_) * 32, smem + _sl + 2048 + (tid << 3));              \
  GLOAD_LDS16(pA[2] + (s_) * 32, smem + _sl + 4096 + (tid << 3));              \
  GLOAD_LDS16(pA[3] + (s_) * 32, smem + _sl + 6144 + (tid << 3));              \
  GLOAD_LDS16(pB[0] + KOFS(s_), smem + _sl + 8192 + (tid << 3));               \
  GLOAD_LDS16(pB[1] + KOFS(s_), smem + _sl + 10240 + (tid << 3));              \
} while (0)

// fragment reads: 64B rows; byte = row*64 + ((G ^ ((row>>1)&3))<<4), G=lane>>4
#define AFRAG(sl_, row_)                                                       \
  (*(const short8*)((const char*)smem + (sl_) * 24576 + (row_) * 64 +        \
      (((lane >> 4) ^ (((row_) >> 1) & 3)) << 4)))
#define BFRAG(sl_, row_)                                                       \
  (*(const short8*)((const char*)smem + (sl_) * 24576 + 16384 + (row_) * 64 + \
      (((lane >> 4) ^ (((row_) >> 1) & 3)) << 4)))

__global__ __launch_bounds__(256, 2) void gemm_kernel(
    const unsigned short* __restrict__ Wt, const unsigned short* __restrict__ xt,
    const float* __restrict__ bias, float* __restrict__ out) {
  __shared__ __align__(1024) unsigned short smem[36864];  // 72 KiB

  // XCD swizzle (784 % 8 == 0): each XCD gets 98 consecutive n-tiles.
  const int bid   = blockIdx.x;
  const int ntile = (bid & 7) * 98 + (bid >> 3);
  const int n0    = ntile << 7;   // *128

  const int tid  = threadIdx.x;
  const int lane = tid & 63;
  const int w    = tid >> 6;
  const int wm   = w >> 1;       // 0..1 (o half: 128 rows)
  const int wn   = w & 1;        // 0..1 (n half: 64 rows)
  const int la15 = lane & 15;

  // staging sources: thread t covers row = r*64 + (t>>2), stored granule t&3;
  // source logical granule = (t&3) ^ ((row>>1)&3) = (t&3) ^ ((t>>3)&3).
  const int srow = tid >> 2;
  const int sg   = (tid & 3) ^ ((tid >> 3) & 3);
  const unsigned short* pA[4];
  const unsigned short* pB[2];
#pragma unroll
  for (int r = 0; r < 4; ++r)
    pA[r] = Wt + (size_t)(r * 64 + srow) * D_DIM + sg * 8;
#pragma unroll
  for (int r = 0; r < 2; ++r) {
    const int n_g = n0 + r * 64 + srow;
    const int b   = n_g / 3136;
    const int s   = n_g - b * 3136;
    const int oh  = s / 56, ow = s - oh * 56;
    pB[r] = xt + (((size_t)b * XT_H + oh) * XT_H + ow) * 128 + sg * 8;
  }

  f32x4 acc[8][4] = {};

  // ---- prologue: stage slices 0,1 ----
  STAGE_S(0);
  STAGE_S(1);
  asm volatile("s_waitcnt vmcnt(6)" ::: "memory");   // slice 0 landed
  __builtin_amdgcn_s_barrier();

#pragma unroll
  for (int s = 0; s < 36; ++s) {
    const int sl = s % 3;

    // ---- fragment reads for slice s ----
    short8 afr[8], bfr[4];
#pragma unroll
    for (int mi = 0; mi < 8; ++mi)
      afr[mi] = AFRAG(sl, (wm << 7) + (mi << 4) + la15);
#pragma unroll
    for (int ni = 0; ni < 4; ++ni)
      bfr[ni] = BFRAG(sl, (wn << 6) + (ni << 4) + la15);

    // ---- stage slice s+2 into slot (s+2)%3 (freed by barrier s-1) ----
    if (s + 2 < 36) STAGE_S(s + 2);

    // ---- MFMA cluster (compiler inserts fine-grained lgkmcnt) ----
    __builtin_amdgcn_s_setprio(1);
#pragma unroll
    for (int mi = 0; mi < 8; ++mi)
#pragma unroll
      for (int ni = 0; ni < 4; ++ni)
        acc[mi][ni] = __builtin_amdgcn_mfma_f32_16x16x32_bf16(
            afr[mi], bfr[ni], acc[mi][ni], 0, 0, 0);
    __builtin_amdgcn_s_setprio(0);

    // ---- counted wait (slice s+1 landed); barrier ----
    if (s < 34)       asm volatile("s_waitcnt vmcnt(6)" ::: "memory");
    else if (s == 34) asm volatile("s_waitcnt vmcnt(0)" ::: "memory");
    if (s < 35) __builtin_amdgcn_s_barrier();
  }

  // ---- epilogue: D row = o ((lane>>4)*4+reg), col = n (lane&15) ----
  const int lr = (lane >> 4) << 2;
#pragma unroll
  for (int ni = 0; ni < 4; ++ni) {
    const int ng = n0 + (wn << 6) + (ni << 4) + la15;
    const int b  = ng / 3136;
    const int s  = ng - b * 3136;
    float* op = out + (size_t)b * (O_DIM * 3136) + s;
#pragma unroll
    for (int mi = 0; mi < 8; ++mi) {
      const int og = (wm << 7) + (mi << 4) + lr;
#pragma unroll
      for (int r = 0; r < 4; ++r)
        op[(size_t)(og + r) * 3136] = acc[mi][ni][r] + 2.0f * bias[og + r];
    }
  }
}

// ---------------------------------------------------------------------------
extern "C" void kernel_launch(void* const* d_in, const int* in_sizes, int n_in,
                              void* d_out, int out_size, void* d_ws, size_t ws_size,
                              hipStream_t stream) {
  const float* x    = (const float*)d_in[0];
  const float* S1s  = (const float*)d_in[1];
  const float* U1s  = (const float*)d_in[2];
  const float* U2s  = (const float*)d_in[3];
  const float* S2s  = (const float*)d_in[4];
  const float* bias = (const float*)d_in[5];
  float* out = (float*)d_out;
  (void)ws_size;

  unsigned short* xt = (unsigned short*)d_ws;
  unsigned short* Wt = (unsigned short*)((char*)d_ws + (size_t)32 * XT_H * XT_ROW * 2);

  pad_kernel<<<dim3(32 * XT_H), dim3(256), 0, stream>>>(x, xt);
  wt_kernel<<<dim3(72), dim3(256), 0, stream>>>(S1s, U1s, U2s, S2s, Wt);
  gemm_kernel<<<dim3(784), dim3(256), 0, stream>>>(Wt, xt, bias, out);
}